// Round 10
// baseline (386.252 us; speedup 1.0000x reference)
//
#include <hip/hip_runtime.h>
#include <math.h>

#define NSEQ 2048
#define DDIM 1024
#define BSZ  4
#define BM 128
#define BN 128
#define BK 64   // 32 MFMAs per barrier-pair

typedef short bf16x8 __attribute__((ext_vector_type(8)));
typedef float f32x4 __attribute__((ext_vector_type(4)));
typedef unsigned int u32;
typedef unsigned short u16;

__device__ __forceinline__ u16 f2bf(float f) {
  union { float f; u32 u; } x; x.f = f;
  u32 r = x.u + 0x7FFFu + ((x.u >> 16) & 1u);
  return (u16)(r >> 16);
}
__device__ __forceinline__ float bf2f(u16 h) {
  union { u32 u; float f; } x; x.u = ((u32)h) << 16; return x.f;
}
__device__ __forceinline__ float sigmoidf_(float x) {
  return 1.0f / (1.0f + expf(-x));
}

// Async 16B/lane global->LDS. LDS dest is wave-uniform base + lane*16.
__device__ __forceinline__ void async_copy16(const u16* g, u16* l) {
  __builtin_amdgcn_global_load_lds(
      (const __attribute__((address_space(1))) u32*)g,
      (__attribute__((address_space(3))) u32*)l, 16, 0, 0);
}

// LDS tile: 128 rows x 64 bf16. 16 chunks of 8 rows (1KB each).
// XOR swizzle: global 16B-unit q of row r stored at slot q ^ (r&7).
// Reads (16 lanes, fixed quad) hit every bank exactly 2x -> free (m136).
__device__ __forceinline__ void stage_tile(const u16* __restrict__ gsrc, size_t ld,
                                           int k0, u16* lds, int tid) {
  const int wave = tid >> 6, lane = tid & 63;
  const int rr = lane >> 3;
  const int q  = (lane & 7) ^ rr;
#pragma unroll
  for (int j = 0; j < 4; ++j) {
    const int c = j * 4 + wave;
    async_copy16(gsrc + (size_t)(c * 8 + rr) * ld + k0 + q * 8, lds + c * 512);
  }
}

// One BK=64 MFMA step: 2 k-substeps x 4x4 frags of 16x16x32 per wave.
__device__ __forceinline__ void mfma_step(const u16* Al, const u16* Bl,
                                          int wr, int wc, int l16, int quad,
                                          f32x4 acc[4][4]) {
  const int r7 = l16 & 7;
#pragma unroll
  for (int ks = 0; ks < 2; ++ks) {
    const int s = ((ks * 4 + quad) ^ r7) << 3;
    bf16x8 a[4], b[4];
#pragma unroll
    for (int i = 0; i < 4; ++i) {
      a[i] = *(const bf16x8*)(Al + (wr * 64 + i * 16 + l16) * BK + s);
      b[i] = *(const bf16x8*)(Bl + (wc * 64 + i * 16 + l16) * BK + s);
    }
#pragma unroll
    for (int i = 0; i < 4; ++i)
#pragma unroll
      for (int j = 0; j < 4; ++j)
        acc[i][j] = __builtin_amdgcn_mfma_f32_16x16x32_bf16(a[i], b[j], acc[i][j], 0, 0, 0);
  }
}

__device__ __forceinline__ void zero_acc(f32x4 acc[4][4]) {
#pragma unroll
  for (int i = 0; i < 4; ++i)
#pragma unroll
    for (int j = 0; j < 4; ++j) {
      f32x4 z = {0.f, 0.f, 0.f, 0.f};
      acc[i][j] = z;
    }
}

__device__ __forceinline__ void gemm_loop(const u16* A, size_t lda,
                                          const u16* Bt, size_t ldb, int K,
                                          u16* Al, u16* Bl, int tid,
                                          int wr, int wc, int l16, int quad,
                                          f32x4 acc[4][4]) {
  for (int k0 = 0; k0 < K; k0 += BK) {
    __syncthreads();
    stage_tile(A, lda, k0, Al, tid);
    stage_tile(Bt, ldb, k0, Bl, tid);
    __syncthreads();
    mfma_step(Al, Bl, wr, wc, l16, quad, acc);
  }
}

// Packed-triangular attention: per batch, tile-row `it` holds (it+1) 128x128
// tiles; row i (ri=i&127) is contiguous with length wlen=(it+1)*128 at
// base + T(it)*16384 + ri*wlen. Per-batch size 136*16384 elements.
#define ATT_PB 2228224

// ---------------------------------------------------------------------------
// 0) Fused prep: fp32->bf16 converts, conv repack, v-pad zero, out zero.
// ---------------------------------------------------------------------------
__global__ __launch_bounds__(256) void k_prep(
    const float* __restrict__ x,  const float* __restrict__ Wq,
    const float* __restrict__ Wk, const float* __restrict__ Wv,
    const float* __restrict__ rw, const float* __restrict__ f1w,
    const float* __restrict__ cw,
    u16* __restrict__ xb,  u16* __restrict__ Wqb, u16* __restrict__ Wkb,
    u16* __restrict__ Wvb, u16* __restrict__ rwb, u16* __restrict__ f1wb,
    u16* __restrict__ cwp, u16* __restrict__ vpad, float* __restrict__ outz)
{
  const int blk = blockIdx.x, tid = threadIdx.x;
  const float* s; u16* d; int base;
  if (blk < 8192)       { s = x;   d = xb;   base = blk; }
  else if (blk < 9216)  { s = Wq;  d = Wqb;  base = blk - 8192; }
  else if (blk < 10240) { s = Wk;  d = Wkb;  base = blk - 9216; }
  else if (blk < 11264) { s = Wv;  d = Wvb;  base = blk - 10240; }
  else if (blk < 12288) { s = rw;  d = rwb;  base = blk - 11264; }
  else if (blk < 12800) { s = f1w; d = f1wb; base = blk - 12288; }
  else if (blk < 13824) {
    const int o = blk - 12800, i = tid;
#pragma unroll
    for (int tap = 0; tap < 3; ++tap)
      cwp[(size_t)o * 768 + tap * 256 + i] = f2bf(cw[(size_t)o * 768 + i * 3 + tap]);
    return;
  } else if (blk < 13832) {
    const int e = blk - 13824, bb = e >> 1, which = e & 1;
    u16* row = vpad + (size_t)bb * 2050 * 1024 + (which ? (size_t)2049 * 1024 : 0);
    ushort4 z = {0, 0, 0, 0};
    ((ushort4*)row)[tid] = z;
    return;
  } else {
    // zero d_out accumulator: 8192 floats = 2048 float4 over 8 blocks
    const int e = blk - 13832;
    float4 z = {0.f, 0.f, 0.f, 0.f};
    ((float4*)outz)[e * 256 + tid] = z;
    return;
  }
  const int i = base * 256 + tid;
  const float4 v = ((const float4*)s)[i];
  ushort4 o;
  o.x = f2bf(v.x); o.y = f2bf(v.y); o.z = f2bf(v.z); o.w = f2bf(v.w);
  ((ushort4*)d)[i] = o;
}

// ---------------------------------------------------------------------------
// 1) QKV: qb,kb bf16; v -> vpad AND vT (transposed epilogue for z==2).
//    Grouped block swizzle: 8-row x 8-col groups for L2 reuse.
// ---------------------------------------------------------------------------
__global__ __launch_bounds__(256) void k_qkv(
    const u16* __restrict__ xb, const u16* __restrict__ Wqb,
    const u16* __restrict__ Wkb, const u16* __restrict__ Wvb,
    u16* __restrict__ qb, u16* __restrict__ kb, u16* __restrict__ vpad,
    u16* __restrict__ vT)
{
  __shared__ __align__(16) u16 SM[BM * BK + BN * BK];
  u16* Al = SM;
  u16* Bl = SM + BM * BK;
  const int tid = threadIdx.x, z = blockIdx.z;
  const u16* W = (z == 0) ? Wqb : ((z == 1) ? Wkb : Wvb);
  // swizzle: bid -> (row-block, col-block), groups of 8 rows x 8 cols
  const int bid = blockIdx.y * 64 + blockIdx.x;       // 0..511
  const int grp = bid >> 6, loc = bid & 63;
  const int rowb = grp * 8 + (loc & 7), colb = loc >> 3;
  const int row0 = rowb * BM, col0 = colb * BN;
  const int lane = tid & 63, wave = tid >> 6;
  const int quad = lane >> 4, l16 = lane & 15, wr = wave >> 1, wc = wave & 1;
  f32x4 acc[4][4];
  zero_acc(acc);
  gemm_loop(xb + (size_t)row0 * DDIM, DDIM, W + (size_t)col0 * DDIM, DDIM, DDIM,
            Al, Bl, tid, wr, wc, l16, quad, acc);
  const int b = row0 >> 11, t0 = row0 & 2047;
#pragma unroll
  for (int mi = 0; mi < 4; ++mi)
#pragma unroll
    for (int r = 0; r < 4; ++r) {
      const int grow = row0 + wr * 64 + mi * 16 + quad * 4 + r;
#pragma unroll
      for (int ni = 0; ni < 4; ++ni) {
        const int gcol = col0 + wc * 64 + ni * 16 + l16;
        const u16 hv = f2bf(acc[mi][ni][r]);
        if (z == 2) {
          const int t = grow & 2047;
          vpad[(size_t)b * 2050 * 1024 + 1024 + (size_t)t * 1024 + gcol] = hv;
        } else {
          (z == 0 ? qb : kb)[(size_t)grow * DDIM + gcol] = hv;
        }
      }
    }
  if (z == 2) {
    // transposed write: vT[b][col0+d][t0 + p*64 + t], via LDS scratch.
    // tileT layout [128 d][66 pad] u16 (16.9 KB in SM, staging is dead).
    u16* tileT = SM;
    const int tq = (tid & 15) << 2;
#pragma unroll
    for (int p = 0; p < 2; ++p) {
      __syncthreads();
      if (wr == p) {
#pragma unroll
        for (int mi = 0; mi < 4; ++mi)
#pragma unroll
          for (int r = 0; r < 4; ++r) {
            const int tloc = mi * 16 + quad * 4 + r;       // 0..63
#pragma unroll
            for (int ni = 0; ni < 4; ++ni) {
              const int d = wc * 64 + ni * 16 + l16;       // 0..127
              tileT[d * 66 + tloc] = f2bf(acc[mi][ni][r]);
            }
          }
      }
      __syncthreads();
#pragma unroll
      for (int k = 0; k < 8; ++k) {
        const int d = (k << 4) + (tid >> 4);               // 0..127
        const ushort4 o = *(const ushort4*)(tileT + d * 66 + tq);
        *(ushort4*)(vT + ((size_t)b * DDIM + col0 + d) * NSEQ + t0 + p * 64 + tq) = o;
      }
    }
  }
}

// ---------------------------------------------------------------------------
// 2) Grouped conv as GEMM (K=768 tap-major): convb = conv(v) + bias (bf16)
// ---------------------------------------------------------------------------
__global__ __launch_bounds__(256) void k_conv(
    const u16* __restrict__ vpad, const u16* __restrict__ cwp,
    const float* __restrict__ cb, u16* __restrict__ convb)
{
  __shared__ u16 Al[BM * BK], Bl[BN * BK];
  const int tid = threadIdx.x;
  const int row0 = blockIdx.x * BM;
  const int col0 = blockIdx.y * BN;
  const int g = col0 >> 8;
  const int b = row0 >> 11, t0 = row0 & 2047;
  const u16* vb = vpad + (size_t)b * 2050 * 1024 + 1024;
  const u16* Bbase = cwp + (size_t)col0 * 768;
  const int lane = tid & 63, wave = tid >> 6;
  const int quad = lane >> 4, l16 = lane & 15, wr = wave >> 1, wc = wave & 1;
  const int rr = lane >> 3;
  const int q  = (lane & 7) ^ rr;
  const int gch = g << 8;
  f32x4 acc[4][4];
  zero_acc(acc);
  for (int k0 = 0; k0 < 768; k0 += BK) {
    __syncthreads();
    const int tap = k0 >> 8;            // BK=64 chunks never cross tap bounds
    const int i0 = k0 & 255;
#pragma unroll
    for (int j = 0; j < 4; ++j) {
      const int c = j * 4 + wave;
      const int r = c * 8 + rr;
      async_copy16(vb + (size_t)(t0 + r - 1 + tap) * 1024 + gch + i0 + q * 8,
                   Al + c * 512);
    }
    stage_tile(Bbase, 768, k0, Bl, tid);
    __syncthreads();
    mfma_step(Al, Bl, wr, wc, l16, quad, acc);
  }
#pragma unroll
  for (int mi = 0; mi < 4; ++mi)
#pragma unroll
    for (int r = 0; r < 4; ++r) {
      const int grow = row0 + wr * 64 + mi * 16 + quad * 4 + r;
#pragma unroll
      for (int ni = 0; ni < 4; ++ni) {
        const int gcol = col0 + wc * 64 + ni * 16 + l16;
        convb[(size_t)grow * DDIM + gcol] = f2bf(cb[gcol] + acc[mi][ni][r]);
      }
    }
}

// ---------------------------------------------------------------------------
// 3) Scores: att_packed(fp32) = q k^T / 32 + rel_bias (tri tiles only).
// ---------------------------------------------------------------------------
__global__ __launch_bounds__(256) void k_scores(
    const u16* __restrict__ qb, const u16* __restrict__ kb,
    const float* __restrict__ rb, float* __restrict__ attp)
{
  __shared__ u16 Al[BM * BK], Bl[BN * BK];
  const int b = blockIdx.x, t = blockIdx.y, tid = threadIdx.x;
  int it = 0;
  while ((it + 1) * (it + 2) / 2 <= t) ++it;
  const int jt = t - it * (it + 1) / 2;
  const int row0 = it * BM, col0 = jt * BN;
  const int lane = tid & 63, wave = tid >> 6;
  const int quad = lane >> 4, l16 = lane & 15, wr = wave >> 1, wc = wave & 1;
  f32x4 acc[4][4];
  zero_acc(acc);
  gemm_loop(qb + ((size_t)b * NSEQ + row0) * DDIM, DDIM,
            kb + ((size_t)b * NSEQ + col0) * DDIM, DDIM, DDIM,
            Al, Bl, tid, wr, wc, l16, quad, acc);
  float* abase = attp + (size_t)b * ATT_PB + (size_t)(it * (it + 1) / 2) * 16384;
  const int ldp = (it + 1) * 128;
#pragma unroll
  for (int mi = 0; mi < 4; ++mi)
#pragma unroll
    for (int r = 0; r < 4; ++r) {
      const int ri = wr * 64 + mi * 16 + quad * 4 + r;
      const int gi = row0 + ri;
#pragma unroll
      for (int ni = 0; ni < 4; ++ni) {
        const int j = col0 + wc * 64 + ni * 16 + l16;
        abase[(size_t)ri * ldp + j] =
            acc[mi][ni][r] * 0.03125f + rb[(size_t)gi * NSEQ + j];
      }
    }
}

// ---------------------------------------------------------------------------
// 4) Row softmax: packed fp32 in -> packed NORMALIZED bf16 probs out.
// ---------------------------------------------------------------------------
__global__ __launch_bounds__(256) void k_softmax(const float* __restrict__ attp,
                                                 u16* __restrict__ pp)
{
  const int i = blockIdx.x, b = blockIdx.y;
  const int it = i >> 7;
  const int wlen = (it + 1) << 7;
  const size_t rbase = (size_t)b * ATT_PB +
                       (size_t)(it * (it + 1) / 2) * 16384 + (size_t)(i & 127) * wlen;
  const float* row = attp + rbase;
  u16* orow = pp + rbase;
  const int valid = i + 1;
  const int tid = threadIdx.x;
  const int lane = tid & 63, wid = tid >> 6;

  float v[8];
  float m = -1e30f;
#pragma unroll
  for (int t = 0; t < 8; ++t) {
    const int idx = tid + (t << 8);
    v[t] = (idx < valid) ? row[idx] : -1e30f;
    m = fmaxf(m, v[t]);
  }
#pragma unroll
  for (int off = 32; off; off >>= 1) m = fmaxf(m, __shfl_xor(m, off));
  __shared__ float red[4];
  if (lane == 0) red[wid] = m;
  __syncthreads();
  m = fmaxf(fmaxf(red[0], red[1]), fmaxf(red[2], red[3]));
  __syncthreads();

  float s = 0.f;
#pragma unroll
  for (int t = 0; t < 8; ++t) {
    const int idx = tid + (t << 8);
    float e = (idx < valid) ? expf(v[t] - m) : 0.f;
    v[t] = e;
    s += e;
  }
#pragma unroll
  for (int off = 32; off; off >>= 1) s += __shfl_xor(s, off);
  if (lane == 0) red[wid] = s;
  __syncthreads();
  s = red[0] + red[1] + red[2] + red[3];
  const float inv = 1.0f / s;
#pragma unroll
  for (int t = 0; t < 8; ++t) {
    const int idx = tid + (t << 8);
    if (idx < wlen) orow[idx] = f2bf(v[t] * inv);
  }
}

// ---------------------------------------------------------------------------
// 5) PV (+conv add): buf1b = pp @ v + convb. Longest tiles (it=15) first.
// ---------------------------------------------------------------------------
__global__ __launch_bounds__(256) void k_pv(
    const u16* __restrict__ pp, const u16* __restrict__ vT,
    const u16* __restrict__ convb, u16* __restrict__ buf1b)
{
  __shared__ u16 Al[BM * BK], Bl[BN * BK];
  const int it = 15 - blockIdx.x, nt = blockIdx.y, b = blockIdx.z;
  const int tid = threadIdx.x;
  const int row0 = it * BM, col0 = nt * BN;
  const int K = (it + 1) * BM;
  const int lane = tid & 63, wave = tid >> 6;
  const int quad = lane >> 4, l16 = lane & 15, wr = wave >> 1, wc = wave & 1;
  f32x4 acc[4][4];
  zero_acc(acc);
  gemm_loop(pp + (size_t)b * ATT_PB + (size_t)(it * (it + 1) / 2) * 16384, K,
            vT + ((size_t)b * DDIM + col0) * NSEQ, NSEQ, K,
            Al, Bl, tid, wr, wc, l16, quad, acc);
  const size_t obase = (size_t)b * NSEQ * DDIM;
#pragma unroll
  for (int mi = 0; mi < 4; ++mi)
#pragma unroll
    for (int r = 0; r < 4; ++r) {
      const int grow = row0 + wr * 64 + mi * 16 + quad * 4 + r;
#pragma unroll
      for (int ni = 0; ni < 4; ++ni) {
        const int gcol = col0 + wc * 64 + ni * 16 + l16;
        const size_t idx = obase + (size_t)grow * DDIM + gcol;
        buf1b[idx] = f2bf(acc[mi][ni][r] + bf2f(convb[idx]));
      }
    }
}

// ---------------------------------------------------------------------------
// 6) Residual gate: buf2(bf16) = xb + sigmoid(buf1b @ rw^T + rb) * buf1b
// ---------------------------------------------------------------------------
__global__ __launch_bounds__(256) void k_resgate(
    const u16* __restrict__ buf1b, const u16* __restrict__ rwb,
    const float* __restrict__ rbias, const u16* __restrict__ xb,
    u16* __restrict__ buf2)
{
  __shared__ u16 Al[BM * BK], Bl[BN * BK];
  const int tid = threadIdx.x;
  const int bid = blockIdx.y * 64 + blockIdx.x;
  const int grp = bid >> 6, loc = bid & 63;
  const int row0 = (grp * 8 + (loc & 7)) * BM, col0 = (loc >> 3) * BN;
  const int lane = tid & 63, wave = tid >> 6;
  const int quad = lane >> 4, l16 = lane & 15, wr = wave >> 1, wc = wave & 1;
  f32x4 acc[4][4];
  zero_acc(acc);
  gemm_loop(buf1b + (size_t)row0 * DDIM, DDIM, rwb + (size_t)col0 * DDIM, DDIM,
            DDIM, Al, Bl, tid, wr, wc, l16, quad, acc);
#pragma unroll
  for (int mi = 0; mi < 4; ++mi)
#pragma unroll
    for (int r = 0; r < 4; ++r) {
      const int grow = row0 + wr * 64 + mi * 16 + quad * 4 + r;
#pragma unroll
      for (int ni = 0; ni < 4; ++ni) {
        const int gcol = col0 + wc * 64 + ni * 16 + l16;
        const size_t idx = (size_t)grow * DDIM + gcol;
        const float gate = sigmoidf_(acc[mi][ni][r] + rbias[gcol]);
        buf2[idx] = f2bf(bf2f(xb[idx]) + gate * bf2f(buf1b[idx]));
      }
    }
}

// ---------------------------------------------------------------------------
// 7) LayerNorm: bf16 in -> bf16 out (stats fp32)
// ---------------------------------------------------------------------------
__global__ __launch_bounds__(256) void k_ln(
    const u16* __restrict__ buf, const float* __restrict__ gw,
    const float* __restrict__ gb, u16* __restrict__ outb)
{
  const int row = blockIdx.x;
  const u16* p = buf + (size_t)row * DDIM;
  const int tid = threadIdx.x;
  const int lane = tid & 63, wid = tid >> 6;
  const int c = tid << 2;
  const ushort4 raw = *(const ushort4*)(p + c);
  float4 val;
  val.x = bf2f(raw.x); val.y = bf2f(raw.y); val.z = bf2f(raw.z); val.w = bf2f(raw.w);
  float s = val.x + val.y + val.z + val.w;
  float s2 = val.x * val.x + val.y * val.y + val.z * val.z + val.w * val.w;
#pragma unroll
  for (int off = 32; off; off >>= 1) {
    s += __shfl_xor(s, off);
    s2 += __shfl_xor(s2, off);
  }
  __shared__ float r1[4], r2[4];
  if (lane == 0) { r1[wid] = s; r2[wid] = s2; }
  __syncthreads();
  s = r1[0] + r1[1] + r1[2] + r1[3];
  s2 = r2[0] + r2[1] + r2[2] + r2[3];
  const float mean = s * (1.0f / DDIM);
  const float var = s2 * (1.0f / DDIM) - mean * mean;
  const float rstd = rsqrtf(var + 1e-5f);
  const float4 g4 = *(const float4*)(gw + c);
  const float4 b4 = *(const float4*)(gb + c);
  ushort4 o;
  o.x = f2bf((val.x - mean) * rstd * g4.x + b4.x);
  o.y = f2bf((val.y - mean) * rstd * g4.y + b4.y);
  o.z = f2bf((val.z - mean) * rstd * g4.z + b4.z);
  o.w = f2bf((val.w - mean) * rstd * g4.w + b4.w);
  *(ushort4*)(outb + (size_t)row * DDIM + c) = o;
}

// ---------------------------------------------------------------------------
// 8) fc1 + exact GELU + fc2-partial: atomicAdd(out[row], gelu . f2w_slice)
// ---------------------------------------------------------------------------
__global__ __launch_bounds__(256) void k_fc1(
    const u16* __restrict__ A, const u16* __restrict__ W,
    const float* __restrict__ bias, const float* __restrict__ w2,
    float* __restrict__ outacc)
{
  __shared__ u16 Al[BM * BK], Bl[BN * BK];
  const int tid = threadIdx.x;
  const int bid = blockIdx.y * 64 + blockIdx.x;   // grid (64,4)
  const int grp = bid >> 5, loc = bid & 31;
  const int row0 = (grp * 8 + (loc & 7)) * BM, col0 = (loc >> 3) * BN;
  const int lane = tid & 63, wave = tid >> 6;
  const int quad = lane >> 4, l16 = lane & 15, wr = wave >> 1, wc = wave & 1;
  f32x4 acc[4][4];
  zero_acc(acc);
  gemm_loop(A + (size_t)row0 * DDIM, DDIM, W + (size_t)col0 * DDIM, DDIM, DDIM,
            Al, Bl, tid, wr, wc, l16, quad, acc);
  float w4[4], b4[4];
#pragma unroll
  for (int ni = 0; ni < 4; ++ni) {
    const int gcol = col0 + wc * 64 + ni * 16 + l16;
    w4[ni] = w2[gcol];
    b4[ni] = bias[gcol];
  }
#pragma unroll
  for (int mi = 0; mi < 4; ++mi)
#pragma unroll
    for (int r = 0; r < 4; ++r) {
      const int grow = row0 + wr * 64 + mi * 16 + quad * 4 + r;
      float part = 0.f;
#pragma unroll
      for (int ni = 0; ni < 4; ++ni) {
        const float t = acc[mi][ni][r] + b4[ni];
        const float g = 0.5f * t * (1.0f + erff(t * 0.70710678118654752f));
        part = fmaf(g, w4[ni], part);
      }
#pragma unroll
      for (int off = 1; off < 16; off <<= 1) part += __shfl_xor(part, off, 16);
      if (l16 == 0) atomicAdd(outacc + grow, part);
    }
}

// ---------------------------------------------------------------------------
// 9) Finalize: out = sigmoid(out + fc2_b)
// ---------------------------------------------------------------------------
__global__ __launch_bounds__(256) void k_fin(float* __restrict__ out,
                                             const float* __restrict__ b2)
{
  const int i = blockIdx.x * 256 + threadIdx.x;
  out[i] = sigmoidf_(out[i] + b2[0]);
}

// ---------------------------------------------------------------------------
extern "C" void kernel_launch(void* const* d_in, const int* in_sizes, int n_in,
                              void* d_out, int out_size, void* d_ws, size_t ws_size,
                              hipStream_t stream) {
  const float* x    = (const float*)d_in[0];
  const float* Wq   = (const float*)d_in[1];
  const float* Wk   = (const float*)d_in[2];
  const float* Wv   = (const float*)d_in[3];
  const float* rb   = (const float*)d_in[4];
  const float* cw   = (const float*)d_in[5];
  const float* cb   = (const float*)d_in[6];
  const float* rw   = (const float*)d_in[7];
  const float* rbias= (const float*)d_in[8];
  const float* lng  = (const float*)d_in[9];
  const float* lnb  = (const float*)d_in[10];
  const float* f1w  = (const float*)d_in[11];
  const float* f1b  = (const float*)d_in[12];
  const float* f2w  = (const float*)d_in[13];
  const float* f2b  = (const float*)d_in[14];
  float* out = (float*)d_out;
  char* w8 = (char*)d_ws;

  // Memory map (bytes), peak ~147.3 MB:
  u16* xb    = (u16*)(w8 + 0);           // 16.78M (alive until resgate)
  u16* Wqb   = (u16*)(w8 + 16777216);    // 2M
  u16* Wkb   = (u16*)(w8 + 18874368);    // 2M
  u16* Wvb   = (u16*)(w8 + 20971520);    // 2M
  u16* rwb   = (u16*)(w8 + 23068672);    // 2M (until resgate)
  u16* f1wb  = (u16*)(w8 + 25165824);    // 1M (until fc1)
  u16* cwp   = (u16*)(w8 + 26214400);    // 1.5M (until conv)
  u16* qb    = (u16*)(w8 + 27787264);    // 16.78M (dead after scores)
  u16* kb    = (u16*)(w8 + 44564480);    // 16.78M (dead after scores)
  u16* vpad  = (u16*)(w8 + 61341696);    // 16.79M (dead after conv)
  u16* vT    = (u16*)(w8 + 78135296);    // 16.78M (dead after pv)
  float* attp= (float*)(w8 + 94912512);  // 35.65M fp32 packed (dead after softmax)
  u16* convb = (u16*)(w8 + 130564096);   // 16.78M (conv -> pv)
  // Aliases (lifetime-checked):
  u16* pp    = (u16*)(w8 + 27787264);    // 17.83M over qb+kb head (softmax -> pv)
  u16* buf1b = (u16*)(w8 + 45613056);    // 16.78M after pp (pv -> resgate)
  u16* buf2  = (u16*)(w8 + 94912512);    // over attp (resgate -> ln)
  u16* ln16  = (u16*)(w8 + 78135296);    // over vT (ln -> fc1)

  k_prep   <<<dim3(13840),     256, 0, stream>>>(x, Wq, Wk, Wv, rw, f1w, cw,
                                                 xb, Wqb, Wkb, Wvb, rwb, f1wb,
                                                 cwp, vpad, out);
  k_qkv    <<<dim3(64, 8, 3),  256, 0, stream>>>(xb, Wqb, Wkb, Wvb, qb, kb,
                                                 vpad, vT);
  k_conv   <<<dim3(64, 8),     256, 0, stream>>>(vpad, cwp, cb, convb);
  k_scores <<<dim3(4, 136),    256, 0, stream>>>(qb, kb, rb, attp);
  k_softmax<<<dim3(NSEQ, BSZ), 256, 0, stream>>>(attp, pp);
  k_pv     <<<dim3(16, 8, 4),  256, 0, stream>>>(pp, vT, convb, buf1b);
  k_resgate<<<dim3(64, 8),     256, 0, stream>>>(buf1b, rwb, rbias, xb, buf2);
  k_ln     <<<dim3(BSZ * NSEQ),256, 0, stream>>>(buf2, lng, lnb, ln16);
  k_fc1    <<<dim3(64, 4),     256, 0, stream>>>(ln16, f1wb, f1b, f2w, out);
  k_fin    <<<dim3(32),        256, 0, stream>>>(out, f2b);
}

// Round 11
// 377.691 us; speedup vs baseline: 1.0227x; 1.0227x over previous
//
#include <hip/hip_runtime.h>
#include <math.h>

#define NSEQ 2048
#define DDIM 1024
#define BSZ  4
#define BM 128
#define BN 128
#define BK 64   // 32 MFMAs per barrier-pair

typedef short bf16x8 __attribute__((ext_vector_type(8)));
typedef float f32x4 __attribute__((ext_vector_type(4)));
typedef unsigned int u32;
typedef unsigned short u16;

__device__ __forceinline__ u16 f2bf(float f) {
  union { float f; u32 u; } x; x.f = f;
  u32 r = x.u + 0x7FFFu + ((x.u >> 16) & 1u);
  return (u16)(r >> 16);
}
__device__ __forceinline__ float bf2f(u16 h) {
  union { u32 u; float f; } x; x.u = ((u32)h) << 16; return x.f;
}
__device__ __forceinline__ float sigmoidf_(float x) {
  return 1.0f / (1.0f + expf(-x));
}

// Async 16B/lane global->LDS. LDS dest is wave-uniform base + lane*16.
__device__ __forceinline__ void async_copy16(const u16* g, u16* l) {
  __builtin_amdgcn_global_load_lds(
      (const __attribute__((address_space(1))) u32*)g,
      (__attribute__((address_space(3))) u32*)l, 16, 0, 0);
}

// LDS tile: 128 rows x 64 bf16. 16 chunks of 8 rows (1KB each).
// XOR swizzle: global 16B-unit q of row r stored at slot q ^ (r&7).
// Reads (16 lanes, fixed quad) hit every bank exactly 2x -> free (m136).
__device__ __forceinline__ void stage_tile(const u16* __restrict__ gsrc, size_t ld,
                                           int k0, u16* lds, int tid) {
  const int wave = tid >> 6, lane = tid & 63;
  const int rr = lane >> 3;
  const int q  = (lane & 7) ^ rr;
#pragma unroll
  for (int j = 0; j < 4; ++j) {
    const int c = j * 4 + wave;
    async_copy16(gsrc + (size_t)(c * 8 + rr) * ld + k0 + q * 8, lds + c * 512);
  }
}

// One BK=64 MFMA step: 2 k-substeps x 4x4 frags of 16x16x32 per wave.
__device__ __forceinline__ void mfma_step(const u16* Al, const u16* Bl,
                                          int wr, int wc, int l16, int quad,
                                          f32x4 acc[4][4]) {
  const int r7 = l16 & 7;
#pragma unroll
  for (int ks = 0; ks < 2; ++ks) {
    const int s = ((ks * 4 + quad) ^ r7) << 3;
    bf16x8 a[4], b[4];
#pragma unroll
    for (int i = 0; i < 4; ++i) {
      a[i] = *(const bf16x8*)(Al + (wr * 64 + i * 16 + l16) * BK + s);
      b[i] = *(const bf16x8*)(Bl + (wc * 64 + i * 16 + l16) * BK + s);
    }
#pragma unroll
    for (int i = 0; i < 4; ++i)
#pragma unroll
      for (int j = 0; j < 4; ++j)
        acc[i][j] = __builtin_amdgcn_mfma_f32_16x16x32_bf16(a[i], b[j], acc[i][j], 0, 0, 0);
  }
}

__device__ __forceinline__ void zero_acc(f32x4 acc[4][4]) {
#pragma unroll
  for (int i = 0; i < 4; ++i)
#pragma unroll
    for (int j = 0; j < 4; ++j) {
      f32x4 z = {0.f, 0.f, 0.f, 0.f};
      acc[i][j] = z;
    }
}

__device__ __forceinline__ void gemm_loop(const u16* A, size_t lda,
                                          const u16* Bt, size_t ldb, int K,
                                          u16* Al, u16* Bl, int tid,
                                          int wr, int wc, int l16, int quad,
                                          f32x4 acc[4][4]) {
  for (int k0 = 0; k0 < K; k0 += BK) {
    __syncthreads();
    stage_tile(A, lda, k0, Al, tid);
    stage_tile(Bt, ldb, k0, Bl, tid);
    __syncthreads();
    mfma_step(Al, Bl, wr, wc, l16, quad, acc);
  }
}

// Packed-triangular attention: per batch, tile-row `it` holds (it+1) 128x128
// tiles; row i (ri=i&127) is contiguous with length wlen=(it+1)*128 at
// base + T(it)*16384 + ri*wlen. Per-batch size 136*16384 elements.
#define ATT_PB 2228224

// ---------------------------------------------------------------------------
// 0) Fused prep: fp32->bf16 converts, conv repack, v-pad zero, out zero.
// ---------------------------------------------------------------------------
__global__ __launch_bounds__(256) void k_prep(
    const float* __restrict__ x,  const float* __restrict__ Wq,
    const float* __restrict__ Wk, const float* __restrict__ Wv,
    const float* __restrict__ rw, const float* __restrict__ f1w,
    const float* __restrict__ cw,
    u16* __restrict__ xb,  u16* __restrict__ Wqb, u16* __restrict__ Wkb,
    u16* __restrict__ Wvb, u16* __restrict__ rwb, u16* __restrict__ f1wb,
    u16* __restrict__ cwp, u16* __restrict__ vpad, float* __restrict__ outz)
{
  const int blk = blockIdx.x, tid = threadIdx.x;
  const float* s; u16* d; int base;
  if (blk < 8192)       { s = x;   d = xb;   base = blk; }
  else if (blk < 9216)  { s = Wq;  d = Wqb;  base = blk - 8192; }
  else if (blk < 10240) { s = Wk;  d = Wkb;  base = blk - 9216; }
  else if (blk < 11264) { s = Wv;  d = Wvb;  base = blk - 10240; }
  else if (blk < 12288) { s = rw;  d = rwb;  base = blk - 11264; }
  else if (blk < 12800) { s = f1w; d = f1wb; base = blk - 12288; }
  else if (blk < 13824) {
    const int o = blk - 12800, i = tid;
#pragma unroll
    for (int tap = 0; tap < 3; ++tap)
      cwp[(size_t)o * 768 + tap * 256 + i] = f2bf(cw[(size_t)o * 768 + i * 3 + tap]);
    return;
  } else if (blk < 13832) {
    const int e = blk - 13824, bb = e >> 1, which = e & 1;
    u16* row = vpad + (size_t)bb * 2050 * 1024 + (which ? (size_t)2049 * 1024 : 0);
    ushort4 z = {0, 0, 0, 0};
    ((ushort4*)row)[tid] = z;
    return;
  } else {
    // zero d_out accumulator: 8192 floats = 2048 float4 over 8 blocks
    const int e = blk - 13832;
    float4 z = {0.f, 0.f, 0.f, 0.f};
    ((float4*)outz)[e * 256 + tid] = z;
    return;
  }
  const int i = base * 256 + tid;
  const float4 v = ((const float4*)s)[i];
  ushort4 o;
  o.x = f2bf(v.x); o.y = f2bf(v.y); o.z = f2bf(v.z); o.w = f2bf(v.w);
  ((ushort4*)d)[i] = o;
}

// ---------------------------------------------------------------------------
// 1) QKV: qb,kb bf16 [8192][1024]; v bf16 into padded [4][2050][1024]
//    (R9 form: natural grid order, no fused transpose — VGPR 80, occ 26%)
// ---------------------------------------------------------------------------
__global__ __launch_bounds__(256) void k_qkv(
    const u16* __restrict__ xb, const u16* __restrict__ Wqb,
    const u16* __restrict__ Wkb, const u16* __restrict__ Wvb,
    u16* __restrict__ qb, u16* __restrict__ kb, u16* __restrict__ vpad)
{
  __shared__ u16 Al[BM * BK], Bl[BN * BK];
  const int tid = threadIdx.x, z = blockIdx.z;
  const u16* W = (z == 0) ? Wqb : ((z == 1) ? Wkb : Wvb);
  const int row0 = blockIdx.x * BM, col0 = blockIdx.y * BN;
  const int lane = tid & 63, wave = tid >> 6;
  const int quad = lane >> 4, l16 = lane & 15, wr = wave >> 1, wc = wave & 1;
  f32x4 acc[4][4];
  zero_acc(acc);
  gemm_loop(xb + (size_t)row0 * DDIM, DDIM, W + (size_t)col0 * DDIM, DDIM, DDIM,
            Al, Bl, tid, wr, wc, l16, quad, acc);
#pragma unroll
  for (int mi = 0; mi < 4; ++mi)
#pragma unroll
    for (int r = 0; r < 4; ++r) {
      const int grow = row0 + wr * 64 + mi * 16 + quad * 4 + r;
#pragma unroll
      for (int ni = 0; ni < 4; ++ni) {
        const int gcol = col0 + wc * 64 + ni * 16 + l16;
        const u16 hv = f2bf(acc[mi][ni][r]);
        if (z == 2) {
          const int b = grow >> 11, t = grow & 2047;
          vpad[(size_t)b * 2050 * 1024 + 1024 + (size_t)t * 1024 + gcol] = hv;
        } else {
          (z == 0 ? qb : kb)[(size_t)grow * DDIM + gcol] = hv;
        }
      }
    }
}

// ---------------------------------------------------------------------------
// 2) v -> vT bf16 [b][d][t]
// ---------------------------------------------------------------------------
__global__ __launch_bounds__(256) void k_vt(const u16* __restrict__ vpad,
                                            u16* __restrict__ vT)
{
  __shared__ u16 tile[64][72];
  const int t0 = blockIdx.x * 64, d0 = blockIdx.y * 64, b = blockIdx.z;
  const int tid = threadIdx.x;
  const u16* vb = vpad + (size_t)b * 2050 * 1024 + 1024;
#pragma unroll
  for (int p = 0; p < 4; ++p) {
    const int r = p * 16 + (tid >> 4), c = (tid & 15) << 2;
    const ushort4 v4 = *(const ushort4*)(vb + (size_t)(t0 + r) * 1024 + d0 + c);
    tile[r][c] = v4.x; tile[r][c + 1] = v4.y; tile[r][c + 2] = v4.z; tile[r][c + 3] = v4.w;
  }
  __syncthreads();
  u16* ob = vT + (size_t)b * DDIM * NSEQ;
#pragma unroll
  for (int p = 0; p < 4; ++p) {
    const int d = p * 16 + (tid >> 4), t = (tid & 15) << 2;
    ushort4 o;
    o.x = tile[t][d]; o.y = tile[t + 1][d]; o.z = tile[t + 2][d]; o.w = tile[t + 3][d];
    *(ushort4*)(ob + (size_t)(d0 + d) * NSEQ + t0 + t) = o;
  }
}

// ---------------------------------------------------------------------------
// 3) Grouped conv as GEMM (K=768 tap-major): convb = conv(v) + bias (bf16)
// ---------------------------------------------------------------------------
__global__ __launch_bounds__(256) void k_conv(
    const u16* __restrict__ vpad, const u16* __restrict__ cwp,
    const float* __restrict__ cb, u16* __restrict__ convb)
{
  __shared__ u16 Al[BM * BK], Bl[BN * BK];
  const int tid = threadIdx.x;
  const int row0 = blockIdx.x * BM;
  const int col0 = blockIdx.y * BN;
  const int g = col0 >> 8;
  const int b = row0 >> 11, t0 = row0 & 2047;
  const u16* vb = vpad + (size_t)b * 2050 * 1024 + 1024;
  const u16* Bbase = cwp + (size_t)col0 * 768;
  const int lane = tid & 63, wave = tid >> 6;
  const int quad = lane >> 4, l16 = lane & 15, wr = wave >> 1, wc = wave & 1;
  const int rr = lane >> 3;
  const int q  = (lane & 7) ^ rr;
  const int gch = g << 8;
  f32x4 acc[4][4];
  zero_acc(acc);
  for (int k0 = 0; k0 < 768; k0 += BK) {
    __syncthreads();
    const int tap = k0 >> 8;            // BK=64 chunks never cross tap bounds
    const int i0 = k0 & 255;
#pragma unroll
    for (int j = 0; j < 4; ++j) {
      const int c = j * 4 + wave;
      const int r = c * 8 + rr;
      async_copy16(vb + (size_t)(t0 + r - 1 + tap) * 1024 + gch + i0 + q * 8,
                   Al + c * 512);
    }
    stage_tile(Bbase, 768, k0, Bl, tid);
    __syncthreads();
    mfma_step(Al, Bl, wr, wc, l16, quad, acc);
  }
#pragma unroll
  for (int mi = 0; mi < 4; ++mi)
#pragma unroll
    for (int r = 0; r < 4; ++r) {
      const int grow = row0 + wr * 64 + mi * 16 + quad * 4 + r;
#pragma unroll
      for (int ni = 0; ni < 4; ++ni) {
        const int gcol = col0 + wc * 64 + ni * 16 + l16;
        convb[(size_t)grow * DDIM + gcol] = f2bf(cb[gcol] + acc[mi][ni][r]);
      }
    }
}

// ---------------------------------------------------------------------------
// 4) Scores: att_packed(fp32) = q k^T / 32 + rel_bias (tri tiles only).
// ---------------------------------------------------------------------------
__global__ __launch_bounds__(256) void k_scores(
    const u16* __restrict__ qb, const u16* __restrict__ kb,
    const float* __restrict__ rb, float* __restrict__ attp)
{
  __shared__ u16 Al[BM * BK], Bl[BN * BK];
  const int b = blockIdx.x, t = blockIdx.y, tid = threadIdx.x;
  int it = 0;
  while ((it + 1) * (it + 2) / 2 <= t) ++it;
  const int jt = t - it * (it + 1) / 2;
  const int row0 = it * BM, col0 = jt * BN;
  const int lane = tid & 63, wave = tid >> 6;
  const int quad = lane >> 4, l16 = lane & 15, wr = wave >> 1, wc = wave & 1;
  f32x4 acc[4][4];
  zero_acc(acc);
  gemm_loop(qb + ((size_t)b * NSEQ + row0) * DDIM, DDIM,
            kb + ((size_t)b * NSEQ + col0) * DDIM, DDIM, DDIM,
            Al, Bl, tid, wr, wc, l16, quad, acc);
  float* abase = attp + (size_t)b * ATT_PB + (size_t)(it * (it + 1) / 2) * 16384;
  const int ldp = (it + 1) * 128;
#pragma unroll
  for (int mi = 0; mi < 4; ++mi)
#pragma unroll
    for (int r = 0; r < 4; ++r) {
      const int ri = wr * 64 + mi * 16 + quad * 4 + r;
      const int gi = row0 + ri;
#pragma unroll
      for (int ni = 0; ni < 4; ++ni) {
        const int j = col0 + wc * 64 + ni * 16 + l16;
        abase[(size_t)ri * ldp + j] =
            acc[mi][ni][r] * 0.03125f + rb[(size_t)gi * NSEQ + j];
      }
    }
}

// ---------------------------------------------------------------------------
// 5) Row softmax: packed fp32 in -> packed NORMALIZED bf16 probs out.
// ---------------------------------------------------------------------------
__global__ __launch_bounds__(256) void k_softmax(const float* __restrict__ attp,
                                                 u16* __restrict__ pp)
{
  const int i = blockIdx.x, b = blockIdx.y;
  const int it = i >> 7;
  const int wlen = (it + 1) << 7;
  const size_t rbase = (size_t)b * ATT_PB +
                       (size_t)(it * (it + 1) / 2) * 16384 + (size_t)(i & 127) * wlen;
  const float* row = attp + rbase;
  u16* orow = pp + rbase;
  const int valid = i + 1;
  const int tid = threadIdx.x;
  const int lane = tid & 63, wid = tid >> 6;

  float v[8];
  float m = -1e30f;
#pragma unroll
  for (int t = 0; t < 8; ++t) {
    const int idx = tid + (t << 8);
    v[t] = (idx < valid) ? row[idx] : -1e30f;
    m = fmaxf(m, v[t]);
  }
#pragma unroll
  for (int off = 32; off; off >>= 1) m = fmaxf(m, __shfl_xor(m, off));
  __shared__ float red[4];
  if (lane == 0) red[wid] = m;
  __syncthreads();
  m = fmaxf(fmaxf(red[0], red[1]), fmaxf(red[2], red[3]));
  __syncthreads();

  float s = 0.f;
#pragma unroll
  for (int t = 0; t < 8; ++t) {
    const int idx = tid + (t << 8);
    float e = (idx < valid) ? expf(v[t] - m) : 0.f;
    v[t] = e;
    s += e;
  }
#pragma unroll
  for (int off = 32; off; off >>= 1) s += __shfl_xor(s, off);
  if (lane == 0) red[wid] = s;
  __syncthreads();
  s = red[0] + red[1] + red[2] + red[3];
  const float inv = 1.0f / s;
#pragma unroll
  for (int t = 0; t < 8; ++t) {
    const int idx = tid + (t << 8);
    if (idx < wlen) orow[idx] = f2bf(v[t] * inv);
  }
}

// ---------------------------------------------------------------------------
// 6) PV (+conv add): buf1b = pp @ v + convb. Longest tiles (it=15) first.
// ---------------------------------------------------------------------------
__global__ __launch_bounds__(256) void k_pv(
    const u16* __restrict__ pp, const u16* __restrict__ vT,
    const u16* __restrict__ convb, u16* __restrict__ buf1b)
{
  __shared__ u16 Al[BM * BK], Bl[BN * BK];
  const int it = 15 - blockIdx.x, nt = blockIdx.y, b = blockIdx.z;
  const int tid = threadIdx.x;
  const int row0 = it * BM, col0 = nt * BN;
  const int K = (it + 1) * BM;
  const int lane = tid & 63, wave = tid >> 6;
  const int quad = lane >> 4, l16 = lane & 15, wr = wave >> 1, wc = wave & 1;
  f32x4 acc[4][4];
  zero_acc(acc);
  gemm_loop(pp + (size_t)b * ATT_PB + (size_t)(it * (it + 1) / 2) * 16384, K,
            vT + ((size_t)b * DDIM + col0) * NSEQ, NSEQ, K,
            Al, Bl, tid, wr, wc, l16, quad, acc);
  const size_t obase = (size_t)b * NSEQ * DDIM;
#pragma unroll
  for (int mi = 0; mi < 4; ++mi)
#pragma unroll
    for (int r = 0; r < 4; ++r) {
      const int grow = row0 + wr * 64 + mi * 16 + quad * 4 + r;
#pragma unroll
      for (int ni = 0; ni < 4; ++ni) {
        const int gcol = col0 + wc * 64 + ni * 16 + l16;
        const size_t idx = obase + (size_t)grow * DDIM + gcol;
        buf1b[idx] = f2bf(acc[mi][ni][r] + bf2f(convb[idx]));
      }
    }
}

// ---------------------------------------------------------------------------
// 7) Residual gate: buf2(bf16) = xb + sigmoid(buf1b @ rw^T + rb) * buf1b
// ---------------------------------------------------------------------------
__global__ __launch_bounds__(256) void k_resgate(
    const u16* __restrict__ buf1b, const u16* __restrict__ rwb,
    const float* __restrict__ rbias, const u16* __restrict__ xb,
    u16* __restrict__ buf2)
{
  __shared__ u16 Al[BM * BK], Bl[BN * BK];
  const int tid = threadIdx.x;
  const int row0 = blockIdx.x * BM, col0 = blockIdx.y * BN;
  const int lane = tid & 63, wave = tid >> 6;
  const int quad = lane >> 4, l16 = lane & 15, wr = wave >> 1, wc = wave & 1;
  f32x4 acc[4][4];
  zero_acc(acc);
  gemm_loop(buf1b + (size_t)row0 * DDIM, DDIM, rwb + (size_t)col0 * DDIM, DDIM,
            DDIM, Al, Bl, tid, wr, wc, l16, quad, acc);
#pragma unroll
  for (int mi = 0; mi < 4; ++mi)
#pragma unroll
    for (int r = 0; r < 4; ++r) {
      const int grow = row0 + wr * 64 + mi * 16 + quad * 4 + r;
#pragma unroll
      for (int ni = 0; ni < 4; ++ni) {
        const int gcol = col0 + wc * 64 + ni * 16 + l16;
        const size_t idx = (size_t)grow * DDIM + gcol;
        const float gate = sigmoidf_(acc[mi][ni][r] + rbias[gcol]);
        buf2[idx] = f2bf(bf2f(xb[idx]) + gate * bf2f(buf1b[idx]));
      }
    }
}

// ---------------------------------------------------------------------------
// 8) LayerNorm: bf16 in -> bf16 out (stats fp32)
// ---------------------------------------------------------------------------
__global__ __launch_bounds__(256) void k_ln(
    const u16* __restrict__ buf, const float* __restrict__ gw,
    const float* __restrict__ gb, u16* __restrict__ outb)
{
  const int row = blockIdx.x;
  const u16* p = buf + (size_t)row * DDIM;
  const int tid = threadIdx.x;
  const int lane = tid & 63, wid = tid >> 6;
  const int c = tid << 2;
  const ushort4 raw = *(const ushort4*)(p + c);
  float4 val;
  val.x = bf2f(raw.x); val.y = bf2f(raw.y); val.z = bf2f(raw.z); val.w = bf2f(raw.w);
  float s = val.x + val.y + val.z + val.w;
  float s2 = val.x * val.x + val.y * val.y + val.z * val.z + val.w * val.w;
#pragma unroll
  for (int off = 32; off; off >>= 1) {
    s += __shfl_xor(s, off);
    s2 += __shfl_xor(s2, off);
  }
  __shared__ float r1[4], r2[4];
  if (lane == 0) { r1[wid] = s; r2[wid] = s2; }
  __syncthreads();
  s = r1[0] + r1[1] + r1[2] + r1[3];
  s2 = r2[0] + r2[1] + r2[2] + r2[3];
  const float mean = s * (1.0f / DDIM);
  const float var = s2 * (1.0f / DDIM) - mean * mean;
  const float rstd = rsqrtf(var + 1e-5f);
  const float4 g4 = *(const float4*)(gw + c);
  const float4 b4 = *(const float4*)(gb + c);
  ushort4 o;
  o.x = f2bf((val.x - mean) * rstd * g4.x + b4.x);
  o.y = f2bf((val.y - mean) * rstd * g4.y + b4.y);
  o.z = f2bf((val.z - mean) * rstd * g4.z + b4.z);
  o.w = f2bf((val.w - mean) * rstd * g4.w + b4.w);
  *(ushort4*)(outb + (size_t)row * DDIM + c) = o;
}

// ---------------------------------------------------------------------------
// 9) fc1 + exact GELU + fc2-partial: atomicAdd(out[row], gelu . f2w_slice)
// ---------------------------------------------------------------------------
__global__ __launch_bounds__(256) void k_fc1(
    const u16* __restrict__ A, const u16* __restrict__ W,
    const float* __restrict__ bias, const float* __restrict__ w2,
    float* __restrict__ outacc)
{
  __shared__ u16 Al[BM * BK], Bl[BN * BK];
  const int tid = threadIdx.x;
  const int row0 = blockIdx.x * BM, col0 = blockIdx.y * BN;
  const int lane = tid & 63, wave = tid >> 6;
  const int quad = lane >> 4, l16 = lane & 15, wr = wave >> 1, wc = wave & 1;
  f32x4 acc[4][4];
  zero_acc(acc);
  gemm_loop(A + (size_t)row0 * DDIM, DDIM, W + (size_t)col0 * DDIM, DDIM, DDIM,
            Al, Bl, tid, wr, wc, l16, quad, acc);
  float w4[4], b4[4];
#pragma unroll
  for (int ni = 0; ni < 4; ++ni) {
    const int gcol = col0 + wc * 64 + ni * 16 + l16;
    w4[ni] = w2[gcol];
    b4[ni] = bias[gcol];
  }
#pragma unroll
  for (int mi = 0; mi < 4; ++mi)
#pragma unroll
    for (int r = 0; r < 4; ++r) {
      const int grow = row0 + wr * 64 + mi * 16 + quad * 4 + r;
      float part = 0.f;
#pragma unroll
      for (int ni = 0; ni < 4; ++ni) {
        const float t = acc[mi][ni][r] + b4[ni];
        const float g = 0.5f * t * (1.0f + erff(t * 0.70710678118654752f));
        part = fmaf(g, w4[ni], part);
      }
#pragma unroll
      for (int off = 1; off < 16; off <<= 1) part += __shfl_xor(part, off, 16);
      if (l16 == 0) atomicAdd(outacc + grow, part);
    }
}

// ---------------------------------------------------------------------------
// 10) Finalize: out = sigmoid(out + fc2_b)
// ---------------------------------------------------------------------------
__global__ __launch_bounds__(256) void k_fin(float* __restrict__ out,
                                             const float* __restrict__ b2)
{
  const int i = blockIdx.x * 256 + threadIdx.x;
  out[i] = sigmoidf_(out[i] + b2[0]);
}

// ---------------------------------------------------------------------------
extern "C" void kernel_launch(void* const* d_in, const int* in_sizes, int n_in,
                              void* d_out, int out_size, void* d_ws, size_t ws_size,
                              hipStream_t stream) {
  const float* x    = (const float*)d_in[0];
  const float* Wq   = (const float*)d_in[1];
  const float* Wk   = (const float*)d_in[2];
  const float* Wv   = (const float*)d_in[3];
  const float* rb   = (const float*)d_in[4];
  const float* cw   = (const float*)d_in[5];
  const float* cb   = (const float*)d_in[6];
  const float* rw   = (const float*)d_in[7];
  const float* rbias= (const float*)d_in[8];
  const float* lng  = (const float*)d_in[9];
  const float* lnb  = (const float*)d_in[10];
  const float* f1w  = (const float*)d_in[11];
  const float* f1b  = (const float*)d_in[12];
  const float* f2w  = (const float*)d_in[13];
  const float* f2b  = (const float*)d_in[14];
  float* out = (float*)d_out;
  char* w8 = (char*)d_ws;

  // Memory map (bytes), peak ~147.3 MB:
  u16* xb    = (u16*)(w8 + 0);           // 16.78M (alive until resgate)
  u16* Wqb   = (u16*)(w8 + 16777216);    // 2M
  u16* Wkb   = (u16*)(w8 + 18874368);    // 2M
  u16* Wvb   = (u16*)(w8 + 20971520);    // 2M
  u16* rwb   = (u16*)(w8 + 23068672);    // 2M (until resgate)
  u16* f1wb  = (u16*)(w8 + 25165824);    // 1M (until fc1)
  u16* cwp   = (u16*)(w8 + 26214400);    // 1.5M (until conv)
  u16* qb    = (u16*)(w8 + 27787264);    // 16.78M (dead after scores)
  u16* kb    = (u16*)(w8 + 44564480);    // 16.78M (dead after scores)
  u16* vpad  = (u16*)(w8 + 61341696);    // 16.79M (dead after conv)
  u16* vT    = (u16*)(w8 + 78135296);    // 16.78M (dead after pv)
  float* attp= (float*)(w8 + 94912512);  // 35.65M fp32 packed (dead after softmax)
  u16* convb = (u16*)(w8 + 130564096);   // 16.78M (conv -> pv)
  // Aliases (lifetime-checked):
  u16* pp    = (u16*)(w8 + 27787264);    // 17.83M over qb+kb head (softmax -> pv)
  u16* buf1b = (u16*)(w8 + 45613056);    // 16.78M after pp (pv -> resgate)
  u16* buf2  = (u16*)(w8 + 94912512);    // over attp (resgate -> ln)
  u16* ln16  = (u16*)(w8 + 78135296);    // over vT (ln -> fc1)

  k_prep   <<<dim3(13840),     256, 0, stream>>>(x, Wq, Wk, Wv, rw, f1w, cw,
                                                 xb, Wqb, Wkb, Wvb, rwb, f1wb,
                                                 cwp, vpad, out);
  k_qkv    <<<dim3(64, 8, 3),  256, 0, stream>>>(xb, Wqb, Wkb, Wvb, qb, kb, vpad);
  k_vt     <<<dim3(32, 16, 4), 256, 0, stream>>>(vpad, vT);
  k_conv   <<<dim3(64, 8),     256, 0, stream>>>(vpad, cwp, cb, convb);
  k_scores <<<dim3(4, 136),    256, 0, stream>>>(qb, kb, rb, attp);
  k_softmax<<<dim3(NSEQ, BSZ), 256, 0, stream>>>(attp, pp);
  k_pv     <<<dim3(16, 8, 4),  256, 0, stream>>>(pp, vT, convb, buf1b);
  k_resgate<<<dim3(64, 8),     256, 0, stream>>>(buf1b, rwb, rbias, xb, buf2);
  k_ln     <<<dim3(BSZ * NSEQ),256, 0, stream>>>(buf2, lng, lnb, ln16);
  k_fc1    <<<dim3(64, 4),     256, 0, stream>>>(ln16, f1wb, f1b, f2w, out);
  k_fin    <<<dim3(32),        256, 0, stream>>>(out, f2b);
}